// Round 1
// baseline (1883.276 us; speedup 1.0000x reference)
//
#include <hip/hip_runtime.h>
#include <math.h>

#define Bsz   512
#define Tlen  512
#define Din   128
#define Hdim  64
#define NGATE 256   // 4*H
#define ROWS  2
#define NBLK  (Bsz / ROWS)   // 256
#define NTHR  256

// LDS dword layout (dynamic, 33920 dwords = 135680 B):
//   [0, 32768)          W_ih, 256 rows x 32 float4-chunks, chunk-swizzled
//   [32768, 33280)      x double buffer: 2 bufs x (2 rows x 128)
//   [33280, 33792)      gates: 2 rows x 256
//   [33792, 33920)      h: 2 rows x 64
#define LDS_DWORDS 33920

__device__ __forceinline__ float sigmoid_f(float v) {
    return 1.0f / (1.0f + __expf(-v));
}
__device__ __forceinline__ float tanh_f(float v) {
    float a = fabsf(v);
    float e = __expf(2.0f * a);           // >= 1, may be inf
    float r = 1.0f - 2.0f / (e + 1.0f);   // inf -> 1
    return copysignf(r, v);
}

__global__ void __launch_bounds__(NTHR, 1)
lstm_fused(const float* __restrict__ x, const float* __restrict__ W_ih,
           const float* __restrict__ W_hh, const float* __restrict__ b_ih,
           const float* __restrict__ b_hh, float* __restrict__ out)
{
    extern __shared__ float lds[];
    float* wih   = lds;                 // 32768 dwords
    float* xbuf  = lds + 32768;         // 512 dwords
    float* gates = lds + 33280;         // 512 dwords
    float* hbuf  = lds + 33792;         // 128 dwords

    const int tid = threadIdx.x;
    const int g   = tid;                        // gate index 0..255
    const int row_base = blockIdx.x * ROWS;

    // ---- stage W_ih into LDS, 16B-chunk XOR swizzle (bank-conflict-free reads) ----
    {
        const float4* src = reinterpret_cast<const float4*>(W_ih);
        float4* dst = reinterpret_cast<float4*>(wih);
        #pragma unroll
        for (int i = 0; i < 32; ++i) {
            int q  = i * NTHR + tid;     // float4 index 0..8191 (coalesced read)
            int rg = q >> 5;             // gate row
            int c  = q & 31;             // logical chunk
            dst[rg * 32 + (c ^ (rg & 7))] = src[q];
        }
    }

    // ---- W_hh row for this gate into registers (64 VGPR) ----
    float4 whh[16];
    {
        const float4* src = reinterpret_cast<const float4*>(W_hh) + g * 16;
        #pragma unroll
        for (int c = 0; c < 16; ++c) whh[c] = src[c];
    }

    const float bias = b_ih[g] + b_hh[g];

    // ---- init h=0 in LDS, load x(t=0) ----
    if (tid < 128) hbuf[tid] = 0.0f;
    {
        int r = tid >> 7, k = tid & 127;
        xbuf[tid] = x[((size_t)(row_base + r) * Tlen + 0) * Din + k];
    }
    float cstate = 0.0f;
    float hval   = 0.0f;
    __syncthreads();

    int cur = 0;
    const int sw = g & 7;
    const float4* w4 = reinterpret_cast<const float4*>(wih) + g * 32;

    for (int t = 0; t < Tlen; ++t) {
        // prefetch x(t+1) into a register; latency hides under phase-A FMAs
        float xnext = 0.0f;
        if (t + 1 < Tlen) {
            int r = tid >> 7, k = tid & 127;
            xnext = x[((size_t)(row_base + r) * Tlen + (t + 1)) * Din + k];
        }

        // ---- phase A: gates[r][g] = bias + W_ih[g,:].x_t[r] + W_hh[g,:].h[r] ----
        float acc0 = bias, acc1 = bias;
        {
            const float4* xr0 = reinterpret_cast<const float4*>(xbuf + cur * 256);
            const float4* xr1 = reinterpret_cast<const float4*>(xbuf + cur * 256 + 128);
            #pragma unroll 8
            for (int c = 0; c < 32; ++c) {
                float4 w = w4[c ^ sw];   // physical slot c^sw holds logical chunk c
                float4 a = xr0[c];       // uniform broadcast
                float4 b = xr1[c];
                acc0 += w.x * a.x + w.y * a.y + w.z * a.z + w.w * a.w;
                acc1 += w.x * b.x + w.y * b.y + w.z * b.z + w.w * b.w;
            }
        }
        {
            const float4* h0 = reinterpret_cast<const float4*>(hbuf);
            const float4* h1 = reinterpret_cast<const float4*>(hbuf + 64);
            #pragma unroll
            for (int c = 0; c < 16; ++c) {
                float4 w = whh[c];
                float4 a = h0[c];        // uniform broadcast
                float4 b = h1[c];
                acc0 += w.x * a.x + w.y * a.y + w.z * a.z + w.w * a.w;
                acc1 += w.x * b.x + w.y * b.y + w.z * b.z + w.w * b.w;
            }
        }
        gates[g]       = acc0;
        gates[256 + g] = acc1;
        __syncthreads();

        // ---- phase B: elementwise LSTM cell update (threads 0..127) ----
        if (tid < 128) {
            int r = tid >> 6, j = tid & 63;
            const float* gr = gates + r * 256;
            float ig = sigmoid_f(gr[j]);
            float fg = sigmoid_f(gr[64 + j]);
            float gg = tanh_f(gr[128 + j]);
            float og = sigmoid_f(gr[192 + j]);
            cstate = fg * cstate + ig * gg;
            hval   = og * tanh_f(cstate);
            hbuf[r * 64 + j] = hval;
        }
        // commit prefetched x(t+1) into the other buffer
        if (t + 1 < Tlen) xbuf[(cur ^ 1) * 256 + tid] = xnext;
        __syncthreads();
        cur ^= 1;
    }

    if (tid < 128) {
        int r = tid >> 6, j = tid & 63;
        out[(size_t)(row_base + r) * Hdim + j] = hval;
    }
}

extern "C" void kernel_launch(void* const* d_in, const int* in_sizes, int n_in,
                              void* d_out, int out_size, void* d_ws, size_t ws_size,
                              hipStream_t stream) {
    const float* x    = (const float*)d_in[0];
    const float* W_ih = (const float*)d_in[1];
    const float* W_hh = (const float*)d_in[2];
    const float* b_ih = (const float*)d_in[3];
    const float* b_hh = (const float*)d_in[4];
    float* out = (float*)d_out;

    const size_t lds_bytes = (size_t)LDS_DWORDS * 4;  // 135680 < 160 KiB
    hipFuncSetAttribute(reinterpret_cast<const void*>(lstm_fused),
                        hipFuncAttributeMaxDynamicSharedMemorySize, (int)lds_bytes);
    lstm_fused<<<NBLK, NTHR, lds_bytes, stream>>>(x, W_ih, W_hh, b_ih, b_hh, out);
}

// Round 2
// 520.226 us; speedup vs baseline: 3.6201x; 3.6201x over previous
//
#include <hip/hip_runtime.h>
#include <math.h>

// LSTM: B=512, T=512, D=128, H=64. out = h_T [512,64] fp32.
// Two-phase: (1) xg = x @ W_ih^T + b  via bf16 MFMA w/ hi-lo split into d_ws,
//            (2) 512 serial steps, K=64 recurrence, batch-parallel across blocks.
// Fallback to fused single-kernel if ws_size too small.

#define Bsz   512
#define Tlen  512
#define Din   128
#define Hdim  64
#define NGATE 256

typedef __attribute__((ext_vector_type(8))) short short8v;
typedef __attribute__((ext_vector_type(4))) float f32x4;

__device__ __forceinline__ unsigned short f2bf_bits(float f) {
    union { float f; unsigned u; } v; v.f = f;
    unsigned r = v.u + 0x7fff + ((v.u >> 16) & 1);   // round-to-nearest-even
    return (unsigned short)(r >> 16);
}
__device__ __forceinline__ float bf2f(unsigned short b) {
    union { unsigned u; float f; } v; v.u = ((unsigned)b) << 16;
    return v.f;
}

__device__ __forceinline__ void store_xg(float* p, float v) { *p = v; }
__device__ __forceinline__ void store_xg(unsigned short* p, float v) { *p = f2bf_bits(v); }
__device__ __forceinline__ float load_xg(const float* p) { return *p; }
__device__ __forceinline__ float load_xg(const unsigned short* p) { return bf2f(*p); }

__device__ __forceinline__ float sigmoid_f(float v) {
    return 1.0f / (1.0f + __expf(-v));
}
__device__ __forceinline__ float tanh_f(float v) {
    float a = fabsf(v);
    float e = __expf(2.0f * a);
    float r = 1.0f - 2.0f / (e + 1.0f);
    return copysignf(r, v);
}

// ---------------- Phase 1: xg[B*T][256] = x[B*T][128] @ W_ih^T + (b_ih+b_hh) ----
// 2048 blocks x 256 thr (4 waves). Wave w owns gates [64w, 64w+64).
// Each block: 8 M-chunks of 16 rows. bf16 MFMA 16x16x32 with hi/lo split (3 mfma).
template <typename ST>
__global__ __launch_bounds__(256, 1)
void xg_gemm(const float* __restrict__ x, const float* __restrict__ W_ih,
             const float* __restrict__ b_ih, const float* __restrict__ b_hh,
             ST* __restrict__ xg)
{
    const int lane  = threadIdx.x & 63;
    const int wave  = threadIdx.x >> 6;
    const int gbase = wave * 64;
    const int lrow  = lane & 15;
    const int lk8   = (lane >> 4) * 8;

    // B fragments (W_ih^T slices), hi/lo bf16, held in registers for all chunks.
    short8v bhi[4][4], blo[4][4];
    #pragma unroll
    for (int n = 0; n < 4; ++n) {
        #pragma unroll
        for (int s = 0; s < 4; ++s) {
            const float* wp = W_ih + (size_t)(gbase + n * 16 + lrow) * Din + s * 32 + lk8;
            f32x4 v0 = *(const f32x4*)wp;
            f32x4 v1 = *(const f32x4*)(wp + 4);
            #pragma unroll
            for (int j = 0; j < 8; ++j) {
                float f = (j < 4) ? v0[j] : v1[j - 4];
                unsigned short hb = f2bf_bits(f);
                bhi[n][s][j] = (short)hb;
                blo[n][s][j] = (short)f2bf_bits(f - bf2f(hb));
            }
        }
    }
    float bias_n[4];
    #pragma unroll
    for (int n = 0; n < 4; ++n) {
        int col = gbase + n * 16 + lrow;
        bias_n[n] = b_ih[col] + b_hh[col];
    }

    const int chunk0 = blockIdx.x * 8;
    for (int cc = 0; cc < 8; ++cc) {
        const int m0 = (chunk0 + cc) * 16;
        f32x4 acc[4];
        #pragma unroll
        for (int n = 0; n < 4; ++n) acc[n] = (f32x4){0.f, 0.f, 0.f, 0.f};

        #pragma unroll
        for (int s = 0; s < 4; ++s) {
            const float* xp = x + (size_t)(m0 + lrow) * Din + s * 32 + lk8;
            f32x4 a0 = *(const f32x4*)xp;
            f32x4 a1 = *(const f32x4*)(xp + 4);
            short8v ahi, alo;
            #pragma unroll
            for (int j = 0; j < 8; ++j) {
                float f = (j < 4) ? a0[j] : a1[j - 4];
                unsigned short hb = f2bf_bits(f);
                ahi[j] = (short)hb;
                alo[j] = (short)f2bf_bits(f - bf2f(hb));
            }
            #pragma unroll
            for (int n = 0; n < 4; ++n) {
                acc[n] = __builtin_amdgcn_mfma_f32_16x16x32_bf16(ahi, bhi[n][s], acc[n], 0, 0, 0);
                acc[n] = __builtin_amdgcn_mfma_f32_16x16x32_bf16(alo, bhi[n][s], acc[n], 0, 0, 0);
                acc[n] = __builtin_amdgcn_mfma_f32_16x16x32_bf16(ahi, blo[n][s], acc[n], 0, 0, 0);
            }
        }
        // C/D layout (m89-verified): col = lane&15, row = (lane>>4)*4 + reg
        #pragma unroll
        for (int n = 0; n < 4; ++n) {
            const int col = gbase + n * 16 + lrow;
            #pragma unroll
            for (int r = 0; r < 4; ++r) {
                const int row = m0 + (lane >> 4) * 4 + r;
                store_xg(xg + (size_t)row * NGATE + col, acc[n][r] + bias_n[n]);
            }
        }
    }
}

// ---------------- Phase 2: serial recurrence, K=64 ----------------------------
// 256 blocks x 512 thr (8 waves, 2/SIMD). Thread (row=tid>>8, gate=tid&255).
// W_hh row in 16 NAMED float4 regs (forces register residency). h via LDS
// broadcast (conflict-free). 2 barriers/step.
#define DOT4(A, W, Hc) do { f32x4 _h = (Hc); \
    A = fmaf((W)[0], _h[0], A); A = fmaf((W)[1], _h[1], A); \
    A = fmaf((W)[2], _h[2], A); A = fmaf((W)[3], _h[3], A); } while (0)

template <typename ST>
__global__ __launch_bounds__(512, 1)
void lstm_rec(const ST* __restrict__ xg, const float* __restrict__ W_hh,
              const float* __restrict__ b_ih, const float* __restrict__ b_hh,
              float* __restrict__ out)
{
    __shared__ float hbuf[2 * Hdim];
    __shared__ float gates[2 * NGATE];
    const int tid = threadIdx.x;
    const int row = tid >> 8;          // 0..1
    const int g   = tid & 255;         // gate 0..255
    const int grow = blockIdx.x * 2 + row;

    const f32x4* wp = (const f32x4*)(W_hh + (size_t)g * Hdim);
    f32x4 w0 = wp[0],  w1 = wp[1],  w2 = wp[2],  w3 = wp[3];
    f32x4 w4 = wp[4],  w5 = wp[5],  w6 = wp[6],  w7 = wp[7];
    f32x4 w8 = wp[8],  w9 = wp[9],  w10 = wp[10], w11 = wp[11];
    f32x4 w12 = wp[12], w13 = wp[13], w14 = wp[14], w15 = wp[15];

    if (tid < 128) hbuf[tid] = 0.0f;
    float cstate = 0.0f, hval = 0.0f;

    const ST* xp = xg + (size_t)grow * Tlen * NGATE + g;
    float xcur = load_xg(xp);
    __syncthreads();

    for (int t = 0; t < Tlen; ++t) {
        float xnxt = 0.0f;
        if (t < Tlen - 1) xnxt = load_xg(xp + (size_t)(t + 1) * NGATE);

        const f32x4* hb = (const f32x4*)(hbuf + row * Hdim);  // wave-uniform base
        float a0 = xcur, a1 = 0.0f;   // bias folded into xg in phase 1
        DOT4(a0, w0,  hb[0]);  DOT4(a1, w1,  hb[1]);
        DOT4(a0, w2,  hb[2]);  DOT4(a1, w3,  hb[3]);
        DOT4(a0, w4,  hb[4]);  DOT4(a1, w5,  hb[5]);
        DOT4(a0, w6,  hb[6]);  DOT4(a1, w7,  hb[7]);
        DOT4(a0, w8,  hb[8]);  DOT4(a1, w9,  hb[9]);
        DOT4(a0, w10, hb[10]); DOT4(a1, w11, hb[11]);
        DOT4(a0, w12, hb[12]); DOT4(a1, w13, hb[13]);
        DOT4(a0, w14, hb[14]); DOT4(a1, w15, hb[15]);
        gates[row * NGATE + g] = a0 + a1;
        __syncthreads();

        if (tid < 128) {
            int r = tid >> 6, j = tid & 63;
            const float* gr = gates + r * NGATE;
            float ig = sigmoid_f(gr[j]);
            float fg = sigmoid_f(gr[Hdim + j]);
            float gg = tanh_f(gr[2 * Hdim + j]);
            float og = sigmoid_f(gr[3 * Hdim + j]);
            cstate = fg * cstate + ig * gg;
            hval   = og * tanh_f(cstate);
            hbuf[r * Hdim + j] = hval;
        }
        __syncthreads();
        xcur = xnxt;
    }

    if (tid < 128) {
        int r = tid >> 6, j = tid & 63;
        out[(size_t)(blockIdx.x * 2 + r) * Hdim + j] = hval;
    }
}

// ---------------- Fallback: round-1 fused kernel (proven correct) -------------
#define LDS_DWORDS 33920
__global__ void __launch_bounds__(256, 1)
lstm_fused(const float* __restrict__ x, const float* __restrict__ W_ih,
           const float* __restrict__ W_hh, const float* __restrict__ b_ih,
           const float* __restrict__ b_hh, float* __restrict__ out)
{
    extern __shared__ float lds[];
    float* wih   = lds;
    float* xbuf  = lds + 32768;
    float* gates = lds + 33280;
    float* hbuf  = lds + 33792;

    const int tid = threadIdx.x;
    const int g   = tid;
    const int row_base = blockIdx.x * 2;

    {
        const float4* src = reinterpret_cast<const float4*>(W_ih);
        float4* dst = reinterpret_cast<float4*>(wih);
        #pragma unroll
        for (int i = 0; i < 32; ++i) {
            int q  = i * 256 + tid;
            int rg = q >> 5;
            int c  = q & 31;
            dst[rg * 32 + (c ^ (rg & 7))] = src[q];
        }
    }
    float4 whh[16];
    {
        const float4* src = reinterpret_cast<const float4*>(W_hh) + g * 16;
        #pragma unroll
        for (int c = 0; c < 16; ++c) whh[c] = src[c];
    }
    const float bias = b_ih[g] + b_hh[g];
    if (tid < 128) hbuf[tid] = 0.0f;
    {
        int r = tid >> 7, k = tid & 127;
        xbuf[tid] = x[((size_t)(row_base + r) * Tlen + 0) * Din + k];
    }
    float cstate = 0.0f, hval = 0.0f;
    __syncthreads();

    int cur = 0;
    const int sw = g & 7;
    const float4* w4 = reinterpret_cast<const float4*>(wih) + g * 32;

    for (int t = 0; t < Tlen; ++t) {
        float xnext = 0.0f;
        if (t + 1 < Tlen) {
            int r = tid >> 7, k = tid & 127;
            xnext = x[((size_t)(row_base + r) * Tlen + (t + 1)) * Din + k];
        }
        float acc0 = bias, acc1 = bias;
        {
            const float4* xr0 = reinterpret_cast<const float4*>(xbuf + cur * 256);
            const float4* xr1 = reinterpret_cast<const float4*>(xbuf + cur * 256 + 128);
            #pragma unroll 8
            for (int c = 0; c < 32; ++c) {
                float4 w = w4[c ^ sw];
                float4 a = xr0[c];
                float4 b = xr1[c];
                acc0 += w.x * a.x + w.y * a.y + w.z * a.z + w.w * a.w;
                acc1 += w.x * b.x + w.y * b.y + w.z * b.z + w.w * b.w;
            }
        }
        {
            const float4* h0 = reinterpret_cast<const float4*>(hbuf);
            const float4* h1 = reinterpret_cast<const float4*>(hbuf + 64);
            #pragma unroll
            for (int c = 0; c < 16; ++c) {
                float4 w = whh[c];
                float4 a = h0[c];
                float4 b = h1[c];
                acc0 += w.x * a.x + w.y * a.y + w.z * a.z + w.w * a.w;
                acc1 += w.x * b.x + w.y * b.y + w.z * b.z + w.w * b.w;
            }
        }
        gates[g]       = acc0;
        gates[256 + g] = acc1;
        __syncthreads();

        if (tid < 128) {
            int r = tid >> 6, j = tid & 63;
            const float* gr = gates + r * 256;
            float ig = sigmoid_f(gr[j]);
            float fg = sigmoid_f(gr[64 + j]);
            float gg = tanh_f(gr[128 + j]);
            float og = sigmoid_f(gr[192 + j]);
            cstate = fg * cstate + ig * gg;
            hval   = og * tanh_f(cstate);
            hbuf[r * 64 + j] = hval;
        }
        if (t + 1 < Tlen) xbuf[(cur ^ 1) * 256 + tid] = xnext;
        __syncthreads();
        cur ^= 1;
    }
    if (tid < 128) {
        int r = tid >> 6, j = tid & 63;
        out[(size_t)(row_base + r) * Hdim + j] = hval;
    }
}

extern "C" void kernel_launch(void* const* d_in, const int* in_sizes, int n_in,
                              void* d_out, int out_size, void* d_ws, size_t ws_size,
                              hipStream_t stream) {
    const float* x    = (const float*)d_in[0];
    const float* W_ih = (const float*)d_in[1];
    const float* W_hh = (const float*)d_in[2];
    const float* b_ih = (const float*)d_in[3];
    const float* b_hh = (const float*)d_in[4];
    float* out = (float*)d_out;

    const size_t need32 = (size_t)Bsz * Tlen * NGATE * 4;  // 268 MB
    if (ws_size >= need32) {
        float* xg = (float*)d_ws;
        xg_gemm<float><<<2048, 256, 0, stream>>>(x, W_ih, b_ih, b_hh, xg);
        lstm_rec<float><<<Bsz / 2, 512, 0, stream>>>(xg, W_hh, b_ih, b_hh, out);
    } else if (ws_size >= need32 / 2) {
        unsigned short* xg = (unsigned short*)d_ws;
        xg_gemm<unsigned short><<<2048, 256, 0, stream>>>(x, W_ih, b_ih, b_hh, xg);
        lstm_rec<unsigned short><<<Bsz / 2, 512, 0, stream>>>(xg, W_hh, b_ih, b_hh, out);
    } else {
        const size_t lds_bytes = (size_t)LDS_DWORDS * 4;
        hipFuncSetAttribute(reinterpret_cast<const void*>(lstm_fused),
                            hipFuncAttributeMaxDynamicSharedMemorySize, (int)lds_bytes);
        lstm_fused<<<Bsz / 2, 256, lds_bytes, stream>>>(x, W_ih, W_hh, b_ih, b_hh, out);
    }
}